// Round 2
// baseline (3532.557 us; speedup 1.0000x reference)
//
#include <hip/hip_runtime.h>
#include <math.h>

typedef __bf16 bf16;
typedef __bf16 bf16x8 __attribute__((ext_vector_type(8)));
typedef float f32x4 __attribute__((ext_vector_type(4)));
typedef float f4 __attribute__((ext_vector_type(4)));

constexpr int kNB = 512, kMS = 8, kT = 64, kIN = 360, kH = 230, kOUT = 53;
constexpr int kB  = kNB * kMS;            // 4096
constexpr long kBT = (long)kB * kT;       // 262144
constexpr int kNP  = 768;                 // packed 3H: 16 c-blocks * (r|z|n)*16
constexpr int kKIH = 384;                 // padded IN (12 * 32)
constexpr int kKHH = 256;                 // padded H  (8 * 32)
constexpr int k2H  = 460;
constexpr int kLD  = 464;                 // out/wv row stride (16B aligned)
constexpr int kKW  = 480;                 // padded 2H for K (15 * 32)

// ---------------- workspace layout ----------------
constexpr long SZ_XG    = 2L * kB * kT * kNP * 2;      // 805,306,368
constexpr long SZ_OUT   = kBT * kLD * 2;               // 243,269,632
constexpr long SZ_WIHP  = 2L * kNP * kKIH * 2;
constexpr long SZ_WHHP  = 2L * kNP * kKHH * 2;
constexpr long SZ_WWT   = 512L * kKW * 2;
constexpr long SZ_WST   = 512L * kKW * 2;
constexpr long SZ_BIHP  = 2L * kNP * 4;
constexpr long SZ_BHHP  = 2L * kNP * 4;
constexpr long SZ_VEC   = 2048L * 4;                   // bw|pw|bs|ps padded to 512 fp32 each
constexpr long SZ_SCORE = kBT * 4;
constexpr long SZ_WVF   = (long)kB * kLD * 4;
constexpr long SZ_WVB   = (long)kB * kLD * 2;
constexpr long SZ_S2    = (long)kB * 4;

static inline long align256(long x) { return (x + 255) & ~255L; }

// ---------------- prep: pack/pad/transpose weights (fp32 -> bf16) ----------------
constexpr int R0 = 2 * kNP * kKIH;   // Wih pack
constexpr int R1 = 2 * kNP * kKHH;   // Whh pack
constexpr int R2 = 512 * kKW;        // W_word^T pad
constexpr int R3 = 512 * kKW;        // W_sent^T pad
constexpr int R4 = 2 * kNP;          // b_ih pack (fp32)
constexpr int R5 = 2 * kNP;          // b_hh pack (fp32)
constexpr int R6 = 4 * 512;          // bw|pw|bs|ps pads (fp32)
constexpr long PREP_TOTAL = (long)R0 + R1 + R2 + R3 + R4 + R5 + R6;

__device__ inline bool unpack_n(int n, int& src) {
    int cb = n / 48, w = n % 48, g = w / 16, cc = w & 15;
    int c = cb * 16 + cc;
    src = g * kH + c;
    return c < kH;
}

__launch_bounds__(256)
__global__ void prep_pack(const float* __restrict__ Wihf, const float* __restrict__ Wihr,
                          const float* __restrict__ Whhf, const float* __restrict__ Whhr,
                          const float* __restrict__ bihf, const float* __restrict__ bihr,
                          const float* __restrict__ bhhf, const float* __restrict__ bhhr,
                          const float* __restrict__ Ww,  const float* __restrict__ bw,
                          const float* __restrict__ pw,
                          const float* __restrict__ Wsn, const float* __restrict__ bs,
                          const float* __restrict__ ps,
                          bf16* __restrict__ WihP, bf16* __restrict__ WhhP,
                          bf16* __restrict__ WwT,  bf16* __restrict__ WsT,
                          float* __restrict__ bihP, float* __restrict__ bhhP,
                          float* __restrict__ vecP)
{
    for (long id = (long)blockIdx.x * 256 + threadIdx.x; id < PREP_TOTAL;
         id += (long)gridDim.x * 256) {
        long i = id;
        if (i < R0) {
            int d = (int)(i / (kNP * kKIH)); int r = (int)(i % (kNP * kKIH));
            int n = r / kKIH, k = r % kKIH;
            int src; bool v = unpack_n(n, src) && (k < kIN);
            WihP[i] = v ? (bf16)(d ? Wihr : Wihf)[(long)src * kIN + k] : (bf16)0.f;
            continue;
        }
        i -= R0;
        if (i < R1) {
            int d = (int)(i / (kNP * kKHH)); int r = (int)(i % (kNP * kKHH));
            int n = r / kKHH, k = r % kKHH;
            int src; bool v = unpack_n(n, src) && (k < kH);
            WhhP[i] = v ? (bf16)(d ? Whhr : Whhf)[(long)src * kH + k] : (bf16)0.f;
            continue;
        }
        i -= R1;
        if (i < R2) {
            int n = (int)(i / kKW), k = (int)(i % kKW);
            WwT[i] = (n < k2H && k < k2H) ? (bf16)Ww[(long)k * k2H + n] : (bf16)0.f;
            continue;
        }
        i -= R2;
        if (i < R3) {
            int n = (int)(i / kKW), k = (int)(i % kKW);
            WsT[i] = (n < k2H && k < k2H) ? (bf16)Wsn[(long)k * k2H + n] : (bf16)0.f;
            continue;
        }
        i -= R3;
        if (i < R4) {
            int d = (int)(i / kNP), n = (int)(i % kNP);
            int src; bool v = unpack_n(n, src);
            bihP[i] = v ? (d ? bihr : bihf)[src] : 0.f;
            continue;
        }
        i -= R4;
        if (i < R5) {
            int d = (int)(i / kNP), n = (int)(i % kNP);
            int src; bool v = unpack_n(n, src);
            bhhP[i] = v ? (d ? bhhr : bhhf)[src] : 0.f;
            continue;
        }
        i -= R5;
        {
            int which = (int)(i / 512), n = (int)(i % 512);
            const float* s = (which == 0) ? bw : (which == 1) ? pw : (which == 2) ? bs : ps;
            vecP[i] = (n < k2H) ? s[n] : 0.f;
        }
    }
}

// ---------------- generic 128x128 bf16 MFMA GEMM, C = A @ Bp^T ----------------
// A: (M, lda) of AT (float or bf16); converted to bf16 at LDS staging. Bp: pre-padded
// (nblks*128, ksteps*32) bf16 row-major (row = output col). MODE 0: C[row*ldc+col] =
// bf16(acc + bias[col]); MODE 1: atomicAdd(score[row], sum_col tanh(acc+bias[col])*proj[col]).
template<int MODE, typename AT>
__launch_bounds__(256)
__global__ void gemm_k(const AT* __restrict__ A, int lda, int K, int ksteps,
                       const bf16* __restrict__ Bp, long bStride,
                       bf16* __restrict__ C, int ldc, long cStride,
                       const float* __restrict__ bias, int biasStride,
                       const float* __restrict__ proj,
                       float* __restrict__ score,
                       int nblks, int zc)
{
    __shared__ bf16 As[128][40];
    __shared__ bf16 Bs[128][40];
    const int tid = threadIdx.x;
    // block decode: groups of (8 m-minor x nblks x zc) for A-panel L2/L3 locality
    const int grp = 8 * nblks * zc;
    const int mg = blockIdx.x / grp, sub = blockIdx.x % grp;
    const int mi = sub & 7, rest = sub >> 3;
    const int nblk = rest % nblks, z = rest / nblks;
    const int mblk = mg * 8 + mi;

    const bf16* Bz = Bp + (long)z * bStride;
    const int rowA0 = mblk * 128, rowB0 = nblk * 128;
    const int lane = tid & 63, wave = tid >> 6;
    const int wm = wave >> 1, wn = wave & 1;
    const int quad = lane >> 4, l16 = lane & 15;
    const int ldb = ksteps * 32;

    const int sr0 = tid >> 2, sk0 = (tid & 3) * 8;
    const int sr1 = sr0 + 64;

    f32x4 acc[4][4] = {};

    for (int ks = 0; ks < ksteps; ++ks) {
        const int kk = ks * 32 + sk0;
        const int v = K - kk;
        {
            const AT* pa0 = A + (long)(rowA0 + sr0) * lda + kk;
            const AT* pa1 = A + (long)(rowA0 + sr1) * lda + kk;
            bf16x8 v0, v1;
            if (v >= 8) {
                if constexpr (sizeof(AT) == 2) {
                    v0 = *(const bf16x8*)pa0;
                    v1 = *(const bf16x8*)pa1;
                } else {
                    const f4* p0 = (const f4*)pa0; f4 a0 = p0[0], b0 = p0[1];
                    const f4* p1 = (const f4*)pa1; f4 a1 = p1[0], b1 = p1[1];
                    v0[0]=(bf16)a0[0]; v0[1]=(bf16)a0[1]; v0[2]=(bf16)a0[2]; v0[3]=(bf16)a0[3];
                    v0[4]=(bf16)b0[0]; v0[5]=(bf16)b0[1]; v0[6]=(bf16)b0[2]; v0[7]=(bf16)b0[3];
                    v1[0]=(bf16)a1[0]; v1[1]=(bf16)a1[1]; v1[2]=(bf16)a1[2]; v1[3]=(bf16)a1[3];
                    v1[4]=(bf16)b1[0]; v1[5]=(bf16)b1[1]; v1[6]=(bf16)b1[2]; v1[7]=(bf16)b1[3];
                }
            } else {
                for (int j = 0; j < 8; ++j) {
                    ((bf16*)&v0)[j] = (j < v) ? (bf16)(float)pa0[j] : (bf16)0.f;
                    ((bf16*)&v1)[j] = (j < v) ? (bf16)(float)pa1[j] : (bf16)0.f;
                }
            }
            *(bf16x8*)&As[sr0][sk0] = v0;
            *(bf16x8*)&As[sr1][sk0] = v1;
            // B staging (pre-padded bf16, no guard)
            *(bf16x8*)&Bs[sr0][sk0] = *(const bf16x8*)(Bz + (long)(rowB0 + sr0) * ldb + kk);
            *(bf16x8*)&Bs[sr1][sk0] = *(const bf16x8*)(Bz + (long)(rowB0 + sr1) * ldb + kk);
        }
        __syncthreads();
        bf16x8 af[4], bfr[4];
#pragma unroll
        for (int mt = 0; mt < 4; ++mt) af[mt] = *(const bf16x8*)&As[wm * 64 + mt * 16 + l16][quad * 8];
#pragma unroll
        for (int nt = 0; nt < 4; ++nt) bfr[nt] = *(const bf16x8*)&Bs[wn * 64 + nt * 16 + l16][quad * 8];
#pragma unroll
        for (int mt = 0; mt < 4; ++mt)
#pragma unroll
            for (int nt = 0; nt < 4; ++nt)
                acc[mt][nt] = __builtin_amdgcn_mfma_f32_16x16x32_bf16(af[mt], bfr[nt], acc[mt][nt], 0, 0, 0);
        __syncthreads();
    }

    if constexpr (MODE == 0) {
        bf16* Cz = C + (long)z * cStride;
        const float* bz = bias + (long)z * biasStride;
#pragma unroll
        for (int mt = 0; mt < 4; ++mt)
#pragma unroll
            for (int nt = 0; nt < 4; ++nt) {
                const int col = rowB0 + wn * 64 + nt * 16 + l16;
                const float bv = bz[col];
#pragma unroll
                for (int r = 0; r < 4; ++r) {
                    const int row = rowA0 + wm * 64 + mt * 16 + quad * 4 + r;
                    Cz[(long)row * ldc + col] = (bf16)(acc[mt][nt][r] + bv);
                }
            }
    } else {
#pragma unroll
        for (int mt = 0; mt < 4; ++mt)
#pragma unroll
            for (int r = 0; r < 4; ++r) {
                float s = 0.f;
#pragma unroll
                for (int nt = 0; nt < 4; ++nt) {
                    const int col = rowB0 + wn * 64 + nt * 16 + l16;
                    s += tanhf(acc[mt][nt][r] + bias[col]) * proj[col];
                }
                for (int m = 1; m < 16; m <<= 1) s += __shfl_xor(s, m, 64);
                if (l16 == 0) {
                    const int row = rowA0 + wm * 64 + mt * 16 + quad * 4 + r;
                    atomicAdd(&score[row], s);
                }
            }
    }
}

// ---------------- GRU recurrence: persistent, 32 rows/block, no inter-block sync ----------------
__launch_bounds__(256)
__global__ void gru_rec(const bf16* __restrict__ xg,   // [2][4096][64][768] packed
                        const bf16* __restrict__ Whh,  // [2][768][256] packed/padded
                        const float* __restrict__ bhh, // [2][768] packed
                        bf16* __restrict__ outbuf)     // [262144][464], col = d*230 + c
{
    __shared__ bf16 hbf[32][264];   // padded stride: conflict-free a-frag reads
    __shared__ float hf32[32][233];
    const int tid = threadIdx.x;
    const int d = blockIdx.y;
    const int row0 = blockIdx.x * 32;
    const int lane = tid & 63, wave = tid >> 6;
    const int quad = lane >> 4, l16 = lane & 15;
    const int wave4 = wave * 4;

    {   // zero hidden state (incl. padding)
        bf16* hb = &hbf[0][0];
        for (int i = tid; i < 32 * 264; i += 256) hb[i] = (bf16)0.f;
        float* hf = &hf32[0][0];
        for (int i = tid; i < 32 * 233; i += 256) hf[i] = 0.f;
    }
    __syncthreads();

    const bf16* xgd = xg + (long)d * ((long)kB * kT * kNP);
    const bf16* Wd  = Whh + (long)d * ((long)kNP * kKHH);
    const float* bd = bhh + (long)d * kNP;

    for (int it = 0; it < kT; ++it) {
        const int t = d ? (kT - 1 - it) : it;
        f32x4 acc[2][4][3] = {};   // [mt][cb_local][gate]
#pragma unroll
        for (int ks = 0; ks < 8; ++ks) {
            bf16x8 af0 = *(const bf16x8*)&hbf[l16][ks * 32 + quad * 8];
            bf16x8 af1 = *(const bf16x8*)&hbf[16 + l16][ks * 32 + quad * 8];
#pragma unroll
            for (int cbl = 0; cbl < 4; ++cbl)
#pragma unroll
                for (int g = 0; g < 3; ++g) {
                    const int n = (wave4 + cbl) * 48 + g * 16 + l16;
                    bf16x8 bfr = *(const bf16x8*)(Wd + (long)n * kKHH + ks * 32 + quad * 8);
                    acc[0][cbl][g] = __builtin_amdgcn_mfma_f32_16x16x32_bf16(af0, bfr, acc[0][cbl][g], 0, 0, 0);
                    acc[1][cbl][g] = __builtin_amdgcn_mfma_f32_16x16x32_bf16(af1, bfr, acc[1][cbl][g], 0, 0, 0);
                }
        }
        __syncthreads();   // all MFMA reads of hbf done before gate writes

#pragma unroll
        for (int cbl = 0; cbl < 4; ++cbl) {
            const int cb = wave4 + cbl;
            const int c = cb * 16 + l16;
            const float bdr = bd[cb * 48 + l16];
            const float bdz = bd[cb * 48 + 16 + l16];
            const float bdn = bd[cb * 48 + 32 + l16];
            if (c < kH) {
#pragma unroll
                for (int mt = 0; mt < 2; ++mt)
#pragma unroll
                    for (int r = 0; r < 4; ++r) {
                        const int rl = mt * 16 + quad * 4 + r;
                        const long rg = row0 + rl;
                        const bf16* xrow = xgd + (rg * kT + t) * kNP + cb * 48 + l16;
                        const float xr = (float)xrow[0];
                        const float xz = (float)xrow[16];
                        const float xn = (float)xrow[32];
                        const float hr = acc[mt][cbl][0][r] + bdr;
                        const float hz = acc[mt][cbl][1][r] + bdz;
                        const float hn = acc[mt][cbl][2][r] + bdn;
                        const float rgate = 1.f / (1.f + expf(-(xr + hr)));
                        const float zgate = 1.f / (1.f + expf(-(xz + hz)));
                        const float ngate = tanhf(xn + rgate * hn);
                        const float h2 = (1.f - zgate) * ngate + zgate * hf32[rl][c];
                        hf32[rl][c] = h2;
                        hbf[rl][c] = (bf16)h2;
                        outbuf[(rg * kT + t) * kLD + d * kH + c] = (bf16)h2;
                    }
            }
        }
        __syncthreads();   // gate writes visible before next step's MFMA
    }
}

// ---------------- word attention: softmax over T + weighted sum ----------------
__launch_bounds__(256)
__global__ void word_attn(const float* __restrict__ score, const bf16* __restrict__ outbuf,
                          float* __restrict__ wvf, bf16* __restrict__ wvb)
{
    const int b = blockIdx.x, tid = threadIdx.x;
    __shared__ float alpha[kT];
    if (tid < 64) {
        float v = score[b * kT + tid];
        float m = v;
        for (int off = 32; off; off >>= 1) m = fmaxf(m, __shfl_xor(m, off, 64));
        float e = expf(v - m);
        float s = e;
        for (int off = 32; off; off >>= 1) s += __shfl_xor(s, off, 64);
        alpha[tid] = e / s;
    }
    __syncthreads();
    for (int c = tid; c < k2H; c += 256) {
        float a = 0.f;
        const bf16* p = outbuf + (long)b * kT * kLD + c;
#pragma unroll 8
        for (int t = 0; t < kT; ++t) a += alpha[t] * (float)p[t * kLD];
        wvf[(long)b * kLD + c] = a;
        wvb[(long)b * kLD + c] = (bf16)a;
    }
}

// ---------------- sentence softmax + weighted sum + fc + scatter (fp32 out) ----------------
__launch_bounds__(256)
__global__ void final_sent(const float* __restrict__ score2, const float* __restrict__ wvf,
                           const float* __restrict__ fcW, const float* __restrict__ fcb,
                           const int* __restrict__ pairs, float* __restrict__ outp)
{
    const int nb = blockIdx.x, tid = threadIdx.x;
    __shared__ float beta[kMS];
    __shared__ float sv[k2H];
    if (tid == 0) {
        float m = -1e30f;
        for (int s = 0; s < kMS; ++s) m = fmaxf(m, score2[nb * kMS + s]);
        float e[kMS], sum = 0.f;
        for (int s = 0; s < kMS; ++s) { e[s] = expf(score2[nb * kMS + s] - m); sum += e[s]; }
        for (int s = 0; s < kMS; ++s) beta[s] = e[s] / sum;
    }
    __syncthreads();
    for (int c = tid; c < k2H; c += 256) {
        float a = 0.f;
#pragma unroll
        for (int s = 0; s < kMS; ++s) a += beta[s] * wvf[(long)(nb * kMS + s) * kLD + c];
        sv[c] = a;
    }
    __syncthreads();
    const int lane = tid & 63, wave = tid >> 6;
    const long base = ((long)pairs[nb * 3] * 64 + pairs[nb * 3 + 1] * 8 + pairs[nb * 3 + 2]) * kOUT;
    for (int o = wave; o < kOUT; o += 4) {
        float p = 0.f;
        for (int c = lane; c < k2H; c += 64) p += sv[c] * fcW[(long)o * k2H + c];
        for (int off = 32; off; off >>= 1) p += __shfl_xor(p, off, 64);
        if (lane == 0) outp[base + o] = p + fcb[o];
    }
}

// ---------------- launch ----------------
extern "C" void kernel_launch(void* const* d_in, const int* in_sizes, int n_in,
                              void* d_out, int out_size, void* d_ws, size_t ws_size,
                              hipStream_t stream)
{
    const float* bag  = (const float*)d_in[0];
    const float* Wihf = (const float*)d_in[1];
    const float* Whhf = (const float*)d_in[2];
    const float* bihf = (const float*)d_in[3];
    const float* bhhf = (const float*)d_in[4];
    const float* Wihr = (const float*)d_in[5];
    const float* Whhr = (const float*)d_in[6];
    const float* bihr = (const float*)d_in[7];
    const float* bhhr = (const float*)d_in[8];
    const float* Ww   = (const float*)d_in[9];
    const float* bw   = (const float*)d_in[10];
    const float* pw   = (const float*)d_in[11];
    const float* Wsn  = (const float*)d_in[12];
    const float* bs   = (const float*)d_in[13];
    const float* ps   = (const float*)d_in[14];
    const float* fcW  = (const float*)d_in[15];
    const float* fcb  = (const float*)d_in[16];
    const int* pairs  = (const int*)d_in[17];

    char* ws = (char*)d_ws;
    long off = 0;
    auto alloc = [&](long sz) { void* p = ws + off; off += align256(sz); return p; };
    bf16* xg    = (bf16*)alloc(SZ_XG);
    bf16* outb  = (bf16*)alloc(SZ_OUT);
    bf16* WihP  = (bf16*)alloc(SZ_WIHP);
    bf16* WhhP  = (bf16*)alloc(SZ_WHHP);
    bf16* WwT   = (bf16*)alloc(SZ_WWT);
    bf16* WsT   = (bf16*)alloc(SZ_WST);
    float* bihP = (float*)alloc(SZ_BIHP);
    float* bhhP = (float*)alloc(SZ_BHHP);
    float* vecP = (float*)alloc(SZ_VEC);
    float* score= (float*)alloc(SZ_SCORE);
    float* wvf  = (float*)alloc(SZ_WVF);
    bf16* wvb   = (bf16*)alloc(SZ_WVB);
    float* s2   = (float*)alloc(SZ_S2);
    if ((size_t)off > ws_size) return;  // diagnostic: ws too small -> stub-like absmax

    hipMemsetAsync(d_out, 0, (size_t)out_size * 4, stream);
    hipMemsetAsync(score, 0, SZ_SCORE, stream);
    hipMemsetAsync(s2, 0, SZ_S2, stream);

    prep_pack<<<5781, 256, 0, stream>>>(Wihf, Wihr, Whhf, Whhr, bihf, bihr, bhhf, bhhr,
                                        Ww, bw, pw, Wsn, bs, ps,
                                        WihP, WhhP, WwT, WsT, bihP, bhhP, vecP);

    // input projection: xg[d] = bag @ WihP[d]^T + bihP[d]   (M=262144, Kpad=384, Npacked=768)
    gemm_k<0, float><<<2048 * 6 * 2, 256, 0, stream>>>(bag, kIN, kIN, 12,
                                                       WihP, (long)kNP * kKIH,
                                                       xg, kNP, (long)kB * kT * kNP,
                                                       bihP, kNP, nullptr, nullptr, 6, 2);

    // bidirectional GRU recurrence -> outbuf
    gru_rec<<<dim3(128, 2), 256, 0, stream>>>(xg, WhhP, bhhP, outb);

    // word scores: atomicAdd tanh(out@WwT + bw) . pw  (M=262144, Kpad=480)
    gemm_k<1, bf16><<<2048 * 4, 256, 0, stream>>>(outb, kLD, k2H, 15,
                                                  WwT, 0, nullptr, 0, 0,
                                                  vecP, 0, vecP + 512, score, 4, 1);

    // softmax over T + weighted sum -> word_vec
    word_attn<<<kB, 256, 0, stream>>>(score, outb, wvf, wvb);

    // sentence scores (M=4096)
    gemm_k<1, bf16><<<32 * 4, 256, 0, stream>>>(wvb, kLD, k2H, 15,
                                                WsT, 0, nullptr, 0, 0,
                                                vecP + 1024, 0, vecP + 1536, s2, 4, 1);

    // sentence softmax + fc + scatter
    final_sent<<<kNB, 256, 0, stream>>>(s2, wvf, fcW, fcb, pairs, (float*)d_out);
}

// Round 3
// 2281.560 us; speedup vs baseline: 1.5483x; 1.5483x over previous
//
#include <hip/hip_runtime.h>
#include <math.h>

typedef __bf16 bf16;
typedef __bf16 bf16x8 __attribute__((ext_vector_type(8)));
typedef float f32x4 __attribute__((ext_vector_type(4)));
typedef float f4 __attribute__((ext_vector_type(4)));

constexpr int kNB = 512, kMS = 8, kT = 64, kH = 230, kIN = 360, kOUT = 53;
constexpr int kB  = kNB * kMS;            // 4096
constexpr long kBT = (long)kB * kT;       // 262144
constexpr int kNP  = 768;                 // packed 3H: 16 c-blocks * (r|z|n)*16
constexpr int kKIH = 384;                 // padded IN (12 * 32)
constexpr int kKHH = 256;                 // padded H  (8 * 32)
constexpr int k2H  = 460;
constexpr int kLD  = 464;                 // out/wv row stride (16B aligned)
constexpr int kKW  = 480;                 // padded 2H for K (15 * 32)
constexpr int kXS  = 772;                 // xs LDS row stride: quads -> disjoint bank groups
constexpr int kHB  = 268;                 // hbf LDS row stride

// fast transcendentals (hardware v_exp_f32 / v_rcp_f32)
__device__ inline float fast_sigmoid(float x) {
    return __builtin_amdgcn_rcpf(1.f + __builtin_amdgcn_exp2f(x * -1.442695040888963f));
}
__device__ inline float fast_tanh(float x) {
    return 1.f - 2.f * __builtin_amdgcn_rcpf(1.f + __builtin_amdgcn_exp2f(x * 2.885390081777927f));
}

// ---------------- workspace layout ----------------
constexpr long SZ_XG    = 2L * kB * kT * kNP * 2;
constexpr long SZ_OUT   = kBT * kLD * 2;
constexpr long SZ_WIHP  = 2L * kNP * kKIH * 2;
constexpr long SZ_WHHP  = 2L * kNP * kKHH * 2;
constexpr long SZ_WWT   = 512L * kKW * 2;
constexpr long SZ_WST   = 512L * kKW * 2;
constexpr long SZ_BIHP  = 2L * kNP * 4;
constexpr long SZ_BHHP  = 2L * kNP * 4;
constexpr long SZ_VEC   = 2048L * 4;
constexpr long SZ_SCORE = kBT * 4;
constexpr long SZ_WVF   = (long)kB * kLD * 4;
constexpr long SZ_WVB   = (long)kB * kLD * 2;
constexpr long SZ_S2    = (long)kB * 4;

static inline long align256(long x) { return (x + 255) & ~255L; }

// ---------------- prep: pack/pad/transpose weights (fp32 -> bf16) ----------------
constexpr int R0 = 2 * kNP * kKIH;
constexpr int R1 = 2 * kNP * kKHH;
constexpr int R2 = 512 * kKW;
constexpr int R3 = 512 * kKW;
constexpr int R4 = 2 * kNP;
constexpr int R5 = 2 * kNP;
constexpr int R6 = 4 * 512;
constexpr long PREP_TOTAL = (long)R0 + R1 + R2 + R3 + R4 + R5 + R6;

__device__ inline bool unpack_n(int n, int& src) {
    int cb = n / 48, w = n % 48, g = w / 16, cc = w & 15;
    int c = cb * 16 + cc;
    src = g * kH + c;
    return c < kH;
}

__launch_bounds__(256)
__global__ void prep_pack(const float* __restrict__ Wihf, const float* __restrict__ Wihr,
                          const float* __restrict__ Whhf, const float* __restrict__ Whhr,
                          const float* __restrict__ bihf, const float* __restrict__ bihr,
                          const float* __restrict__ bhhf, const float* __restrict__ bhhr,
                          const float* __restrict__ Ww,  const float* __restrict__ bw,
                          const float* __restrict__ pw,
                          const float* __restrict__ Wsn, const float* __restrict__ bs,
                          const float* __restrict__ ps,
                          bf16* __restrict__ WihP, bf16* __restrict__ WhhP,
                          bf16* __restrict__ WwT,  bf16* __restrict__ WsT,
                          float* __restrict__ bihP, float* __restrict__ bhhP,
                          float* __restrict__ vecP)
{
    for (long id = (long)blockIdx.x * 256 + threadIdx.x; id < PREP_TOTAL;
         id += (long)gridDim.x * 256) {
        long i = id;
        if (i < R0) {
            int d = (int)(i / (kNP * kKIH)); int r = (int)(i % (kNP * kKIH));
            int n = r / kKIH, k = r % kKIH;
            int src; bool v = unpack_n(n, src) && (k < kIN);
            WihP[i] = v ? (bf16)(d ? Wihr : Wihf)[(long)src * kIN + k] : (bf16)0.f;
            continue;
        }
        i -= R0;
        if (i < R1) {
            int d = (int)(i / (kNP * kKHH)); int r = (int)(i % (kNP * kKHH));
            int n = r / kKHH, k = r % kKHH;
            int src; bool v = unpack_n(n, src) && (k < kH);
            WhhP[i] = v ? (bf16)(d ? Whhr : Whhf)[(long)src * kH + k] : (bf16)0.f;
            continue;
        }
        i -= R1;
        if (i < R2) {
            int n = (int)(i / kKW), k = (int)(i % kKW);
            WwT[i] = (n < k2H && k < k2H) ? (bf16)Ww[(long)k * k2H + n] : (bf16)0.f;
            continue;
        }
        i -= R2;
        if (i < R3) {
            int n = (int)(i / kKW), k = (int)(i % kKW);
            WsT[i] = (n < k2H && k < k2H) ? (bf16)Wsn[(long)k * k2H + n] : (bf16)0.f;
            continue;
        }
        i -= R3;
        if (i < R4) {
            int d = (int)(i / kNP), n = (int)(i % kNP);
            int src; bool v = unpack_n(n, src);
            bihP[i] = v ? (d ? bihr : bihf)[src] : 0.f;
            continue;
        }
        i -= R4;
        if (i < R5) {
            int d = (int)(i / kNP), n = (int)(i % kNP);
            int src; bool v = unpack_n(n, src);
            bhhP[i] = v ? (d ? bhhr : bhhf)[src] : 0.f;
            continue;
        }
        i -= R5;
        {
            int which = (int)(i / 512), n = (int)(i % 512);
            const float* s = (which == 0) ? bw : (which == 1) ? pw : (which == 2) ? bs : ps;
            vecP[i] = (n < k2H) ? s[n] : 0.f;
        }
    }
}

// ---------------- generic 128x128 bf16 MFMA GEMM, C = A @ Bp^T ----------------
// MODE 0: C[row*ldc+col] = bf16(acc+bias)  (row-major)
// MODE 2: time-major remap: row=b*64+t stored at row'=t*4096+b
// MODE 1: atomicAdd(score[row], sum_col tanh(acc+bias[col])*proj[col])
template<int MODE, typename AT>
__launch_bounds__(256)
__global__ void gemm_k(const AT* __restrict__ A, int lda, int K, int ksteps,
                       const bf16* __restrict__ Bp, long bStride,
                       bf16* __restrict__ C, int ldc, long cStride,
                       const float* __restrict__ bias, int biasStride,
                       const float* __restrict__ proj,
                       float* __restrict__ score,
                       int nblks, int zc)
{
    __shared__ bf16 As[128][40];
    __shared__ bf16 Bs[128][40];
    const int tid = threadIdx.x;
    // block decode: mi occupies low 3 bits => all same-XCD blocks of a group share one A panel (L2 reuse)
    const int grp = 8 * nblks * zc;
    const int mg = blockIdx.x / grp, sub = blockIdx.x % grp;
    const int mi = sub & 7, rest = sub >> 3;
    const int nblk = rest % nblks, z = rest / nblks;
    const int mblk = mg * 8 + mi;

    const bf16* Bz = Bp + (long)z * bStride;
    const int rowA0 = mblk * 128, rowB0 = nblk * 128;
    const int lane = tid & 63, wave = tid >> 6;
    const int wm = wave >> 1, wn = wave & 1;
    const int quad = lane >> 4, l16 = lane & 15;
    const int ldb = ksteps * 32;

    const int sr0 = tid >> 2, sk0 = (tid & 3) * 8;
    const int sr1 = sr0 + 64;

    f32x4 acc[4][4] = {};

    for (int ks = 0; ks < ksteps; ++ks) {
        const int kk = ks * 32 + sk0;
        const int v = K - kk;
        {
            const AT* pa0 = A + (long)(rowA0 + sr0) * lda + kk;
            const AT* pa1 = A + (long)(rowA0 + sr1) * lda + kk;
            bf16x8 v0, v1;
            if (v >= 8) {
                if constexpr (sizeof(AT) == 2) {
                    v0 = *(const bf16x8*)pa0;
                    v1 = *(const bf16x8*)pa1;
                } else {
                    const f4* p0 = (const f4*)pa0; f4 a0 = p0[0], b0 = p0[1];
                    const f4* p1 = (const f4*)pa1; f4 a1 = p1[0], b1 = p1[1];
                    v0[0]=(bf16)a0[0]; v0[1]=(bf16)a0[1]; v0[2]=(bf16)a0[2]; v0[3]=(bf16)a0[3];
                    v0[4]=(bf16)b0[0]; v0[5]=(bf16)b0[1]; v0[6]=(bf16)b0[2]; v0[7]=(bf16)b0[3];
                    v1[0]=(bf16)a1[0]; v1[1]=(bf16)a1[1]; v1[2]=(bf16)a1[2]; v1[3]=(bf16)a1[3];
                    v1[4]=(bf16)b1[0]; v1[5]=(bf16)b1[1]; v1[6]=(bf16)b1[2]; v1[7]=(bf16)b1[3];
                }
            } else {
                for (int j = 0; j < 8; ++j) {
                    ((bf16*)&v0)[j] = (j < v) ? (bf16)(float)pa0[j] : (bf16)0.f;
                    ((bf16*)&v1)[j] = (j < v) ? (bf16)(float)pa1[j] : (bf16)0.f;
                }
            }
            *(bf16x8*)&As[sr0][sk0] = v0;
            *(bf16x8*)&As[sr1][sk0] = v1;
            *(bf16x8*)&Bs[sr0][sk0] = *(const bf16x8*)(Bz + (long)(rowB0 + sr0) * ldb + kk);
            *(bf16x8*)&Bs[sr1][sk0] = *(const bf16x8*)(Bz + (long)(rowB0 + sr1) * ldb + kk);
        }
        __syncthreads();
        bf16x8 af[4], bfr[4];
#pragma unroll
        for (int mt = 0; mt < 4; ++mt) af[mt] = *(const bf16x8*)&As[wm * 64 + mt * 16 + l16][quad * 8];
#pragma unroll
        for (int nt = 0; nt < 4; ++nt) bfr[nt] = *(const bf16x8*)&Bs[wn * 64 + nt * 16 + l16][quad * 8];
#pragma unroll
        for (int mt = 0; mt < 4; ++mt)
#pragma unroll
            for (int nt = 0; nt < 4; ++nt)
                acc[mt][nt] = __builtin_amdgcn_mfma_f32_16x16x32_bf16(af[mt], bfr[nt], acc[mt][nt], 0, 0, 0);
        __syncthreads();
    }

    if constexpr (MODE == 0 || MODE == 2) {
        bf16* Cz = C + (long)z * cStride;
        const float* bz = bias + (long)z * biasStride;
#pragma unroll
        for (int mt = 0; mt < 4; ++mt)
#pragma unroll
            for (int nt = 0; nt < 4; ++nt) {
                const int col = rowB0 + wn * 64 + nt * 16 + l16;
                const float bv = bz[col];
#pragma unroll
                for (int r = 0; r < 4; ++r) {
                    const int row = rowA0 + wm * 64 + mt * 16 + quad * 4 + r;
                    const int rowp = (MODE == 2) ? ((row & 63) * kB + (row >> 6)) : row;
                    Cz[(long)rowp * ldc + col] = (bf16)(acc[mt][nt][r] + bv);
                }
            }
    } else {
#pragma unroll
        for (int mt = 0; mt < 4; ++mt)
#pragma unroll
            for (int r = 0; r < 4; ++r) {
                float s = 0.f;
#pragma unroll
                for (int nt = 0; nt < 4; ++nt) {
                    const int col = rowB0 + wn * 64 + nt * 16 + l16;
                    s += fast_tanh(acc[mt][nt][r] + bias[col]) * proj[col];
                }
                for (int m = 1; m < 16; m <<= 1) s += __shfl_xor(s, m, 64);
                if (l16 == 0) {
                    const int row = rowA0 + wm * 64 + mt * 16 + quad * 4 + r;
                    atomicAdd(&score[row], s);
                }
            }
    }
}

// ---------------- GRU recurrence v2: 512 thr, xg prefetch, h in regs ----------------
__launch_bounds__(512)
__global__ void gru_rec(const bf16* __restrict__ xg,   // [2][64][4096][768] TIME-MAJOR
                        const bf16* __restrict__ Whh,  // [2][768][256] packed/padded
                        const float* __restrict__ bhh, // [2][768] packed
                        bf16* __restrict__ outbuf)     // [262144][464], col = d*230 + c
{
    __shared__ bf16 hbf[32][kHB];
    __shared__ bf16 xs[32][kXS];
    const int tid = threadIdx.x;
    const int d = blockIdx.y;
    const int row0 = blockIdx.x * 32;
    const int lane = tid & 63, wave = tid >> 6;   // 8 waves
    const int quad = lane >> 4, l16 = lane & 15;
    const int cb0 = wave * 2;

    for (int i = tid; i < 32 * kHB; i += 512) (&hbf[0][0])[i] = (bf16)0.f;

    const bf16* xgd = xg + (long)d * ((long)kT * kB * kNP);
    const bf16* Wd  = Whh + (long)d * ((long)kNP * kKHH);
    const float* bd = bhh + (long)d * kNP;

    // per-thread fp32 hidden-state carry: [mt][cbl][r]
    float hreg[2][2][4] = {};
    // hoisted biases
    float bdr[2], bdz[2], bdn[2];
#pragma unroll
    for (int cbl = 0; cbl < 2; ++cbl) {
        const int cb = cb0 + cbl;
        bdr[cbl] = bd[cb * 48 + l16];
        bdz[cbl] = bd[cb * 48 + 16 + l16];
        bdn[cbl] = bd[cb * 48 + 32 + l16];
    }

    // slab copy geometry: 32*768 bf16 per step; thread -> (row = tid/16, col = (tid%16)*48)
    const int xr_row = tid >> 4, xr_col = (tid & 15) * 48;

    // prefetch slab for t0
    bf16x8 pf[6];
    {
        const int t0 = d ? kT - 1 : 0;
        const bf16* src = xgd + ((long)t0 * kB + row0) * kNP + (long)tid * 48;
#pragma unroll
        for (int j = 0; j < 6; ++j) pf[j] = *(const bf16x8*)(src + j * 8);
    }
    __syncthreads();

    for (int it = 0; it < kT; ++it) {
        const int t = d ? (kT - 1 - it) : it;
        // stage prefetched slab into LDS (consumed after sync1)
#pragma unroll
        for (int j = 0; j < 6; ++j) *(bf16x8*)&xs[xr_row][xr_col + j * 8] = pf[j];

        f32x4 acc[2][2][3] = {};   // [mt][cbl][gate]
#pragma unroll
        for (int ks = 0; ks < 8; ++ks) {
            bf16x8 af0 = *(const bf16x8*)&hbf[l16][ks * 32 + quad * 8];
            bf16x8 af1 = *(const bf16x8*)&hbf[16 + l16][ks * 32 + quad * 8];
#pragma unroll
            for (int cbl = 0; cbl < 2; ++cbl)
#pragma unroll
                for (int g = 0; g < 3; ++g) {
                    const int n = (cb0 + cbl) * 48 + g * 16 + l16;
                    bf16x8 bfr = *(const bf16x8*)(Wd + (long)n * kKHH + ks * 32 + quad * 8);
                    acc[0][cbl][g] = __builtin_amdgcn_mfma_f32_16x16x32_bf16(af0, bfr, acc[0][cbl][g], 0, 0, 0);
                    acc[1][cbl][g] = __builtin_amdgcn_mfma_f32_16x16x32_bf16(af1, bfr, acc[1][cbl][g], 0, 0, 0);
                }
        }
        // prefetch next step's slab (independent of everything above)
        if (it + 1 < kT) {
            const int tn = d ? (kT - 2 - it) : (it + 1);
            const bf16* src = xgd + ((long)tn * kB + row0) * kNP + (long)tid * 48;
#pragma unroll
            for (int j = 0; j < 6; ++j) pf[j] = *(const bf16x8*)(src + j * 8);
        }
        __syncthreads();   // hbf reads + xs writes complete

#pragma unroll
        for (int cbl = 0; cbl < 2; ++cbl) {
            const int cb = cb0 + cbl;
            const int c = cb * 16 + l16;
            if (c < kH) {
#pragma unroll
                for (int mt = 0; mt < 2; ++mt)
#pragma unroll
                    for (int r = 0; r < 4; ++r) {
                        const int rl = mt * 16 + quad * 4 + r;
                        const float xr = (float)xs[rl][cb * 48 + l16];
                        const float xz = (float)xs[rl][cb * 48 + 16 + l16];
                        const float xn = (float)xs[rl][cb * 48 + 32 + l16];
                        const float rgate = fast_sigmoid(xr + acc[mt][cbl][0][r] + bdr[cbl]);
                        const float zgate = fast_sigmoid(xz + acc[mt][cbl][1][r] + bdz[cbl]);
                        const float ngate = fast_tanh(xn + rgate * (acc[mt][cbl][2][r] + bdn[cbl]));
                        const float h2 = (1.f - zgate) * ngate + zgate * hreg[mt][cbl][r];
                        hreg[mt][cbl][r] = h2;
                        hbf[rl][c] = (bf16)h2;
                        outbuf[((long)(row0 + rl) * kT + t) * kLD + d * kH + c] = (bf16)h2;
                    }
            }
        }
        __syncthreads();   // hbf/xs ready for next iteration
    }
}

// ---------------- word attention: softmax over T + weighted sum (coalesced) ----------------
__launch_bounds__(256)
__global__ void word_attn(const float* __restrict__ score, const bf16* __restrict__ outbuf,
                          float* __restrict__ wvf, bf16* __restrict__ wvb)
{
    const int b = blockIdx.x, tid = threadIdx.x;
    __shared__ float alpha[kT];
    if (tid < 64) {
        float v = score[b * kT + tid];
        float m = v;
        for (int off = 32; off; off >>= 1) m = fmaxf(m, __shfl_xor(m, off, 64));
        float e = __builtin_amdgcn_exp2f((v - m) * 1.442695040888963f);
        float s = e;
        for (int off = 32; off; off >>= 1) s += __shfl_xor(s, off, 64);
        alpha[tid] = e / s;
    }
    __syncthreads();
    const bf16* base = outbuf + (long)b * kT * kLD;
    float a0 = 0.f, a1 = 0.f;
    const int c0 = tid, c1 = tid + 256;
#pragma unroll 4
    for (int t = 0; t < kT; ++t) {
        const float al = alpha[t];
        a0 += al * (float)base[t * kLD + c0];
        if (c1 < k2H) a1 += al * (float)base[t * kLD + c1];
    }
    wvf[(long)b * kLD + c0] = a0;
    wvb[(long)b * kLD + c0] = (bf16)a0;
    if (c1 < k2H) {
        wvf[(long)b * kLD + c1] = a1;
        wvb[(long)b * kLD + c1] = (bf16)a1;
    }
}

// ---------------- sentence softmax + weighted sum + fc + scatter (fp32 out) ----------------
__launch_bounds__(256)
__global__ void final_sent(const float* __restrict__ score2, const float* __restrict__ wvf,
                           const float* __restrict__ fcW, const float* __restrict__ fcb,
                           const int* __restrict__ pairs, float* __restrict__ outp)
{
    const int nb = blockIdx.x, tid = threadIdx.x;
    __shared__ float beta[kMS];
    __shared__ float sv[k2H];
    if (tid == 0) {
        float m = -1e30f;
        for (int s = 0; s < kMS; ++s) m = fmaxf(m, score2[nb * kMS + s]);
        float e[kMS], sum = 0.f;
        for (int s = 0; s < kMS; ++s) { e[s] = expf(score2[nb * kMS + s] - m); sum += e[s]; }
        for (int s = 0; s < kMS; ++s) beta[s] = e[s] / sum;
    }
    __syncthreads();
    for (int c = tid; c < k2H; c += 256) {
        float a = 0.f;
#pragma unroll
        for (int s = 0; s < kMS; ++s) a += beta[s] * wvf[(long)(nb * kMS + s) * kLD + c];
        sv[c] = a;
    }
    __syncthreads();
    const int lane = tid & 63, wave = tid >> 6;
    const long base = ((long)pairs[nb * 3] * 64 + pairs[nb * 3 + 1] * 8 + pairs[nb * 3 + 2]) * kOUT;
    for (int o = wave; o < kOUT; o += 4) {
        float p = 0.f;
        for (int c = lane; c < k2H; c += 64) p += sv[c] * fcW[(long)o * k2H + c];
        for (int off = 32; off; off >>= 1) p += __shfl_xor(p, off, 64);
        if (lane == 0) outp[base + o] = p + fcb[o];
    }
}

// ---------------- launch ----------------
extern "C" void kernel_launch(void* const* d_in, const int* in_sizes, int n_in,
                              void* d_out, int out_size, void* d_ws, size_t ws_size,
                              hipStream_t stream)
{
    const float* bag  = (const float*)d_in[0];
    const float* Wihf = (const float*)d_in[1];
    const float* Whhf = (const float*)d_in[2];
    const float* bihf = (const float*)d_in[3];
    const float* bhhf = (const float*)d_in[4];
    const float* Wihr = (const float*)d_in[5];
    const float* Whhr = (const float*)d_in[6];
    const float* bihr = (const float*)d_in[7];
    const float* bhhr = (const float*)d_in[8];
    const float* Ww   = (const float*)d_in[9];
    const float* bw   = (const float*)d_in[10];
    const float* pw   = (const float*)d_in[11];
    const float* Wsn  = (const float*)d_in[12];
    const float* bs   = (const float*)d_in[13];
    const float* ps   = (const float*)d_in[14];
    const float* fcW  = (const float*)d_in[15];
    const float* fcb  = (const float*)d_in[16];
    const int* pairs  = (const int*)d_in[17];

    char* ws = (char*)d_ws;
    long off = 0;
    auto alloc = [&](long sz) { void* p = ws + off; off += align256(sz); return p; };
    bf16* xg    = (bf16*)alloc(SZ_XG);
    bf16* outb  = (bf16*)alloc(SZ_OUT);
    bf16* WihP  = (bf16*)alloc(SZ_WIHP);
    bf16* WhhP  = (bf16*)alloc(SZ_WHHP);
    bf16* WwT   = (bf16*)alloc(SZ_WWT);
    bf16* WsT   = (bf16*)alloc(SZ_WST);
    float* bihP = (float*)alloc(SZ_BIHP);
    float* bhhP = (float*)alloc(SZ_BHHP);
    float* vecP = (float*)alloc(SZ_VEC);
    float* score= (float*)alloc(SZ_SCORE);
    float* wvf  = (float*)alloc(SZ_WVF);
    bf16* wvb   = (bf16*)alloc(SZ_WVB);
    float* s2   = (float*)alloc(SZ_S2);
    if ((size_t)off > ws_size) return;

    hipMemsetAsync(d_out, 0, (size_t)out_size * 4, stream);
    hipMemsetAsync(score, 0, SZ_SCORE, stream);
    hipMemsetAsync(s2, 0, SZ_S2, stream);

    prep_pack<<<5781, 256, 0, stream>>>(Wihf, Wihr, Whhf, Whhr, bihf, bihr, bhhf, bhhr,
                                        Ww, bw, pw, Wsn, bs, ps,
                                        WihP, WhhP, WwT, WsT, bihP, bhhP, vecP);

    // input projection -> xg TIME-MAJOR: xg[d][t][b][:] = bag row (b*64+t) @ WihP[d]^T + bihP[d]
    gemm_k<2, float><<<2048 * 6 * 2, 256, 0, stream>>>(bag, kIN, kIN, 12,
                                                       WihP, (long)kNP * kKIH,
                                                       xg, kNP, (long)kT * kB * kNP,
                                                       bihP, kNP, nullptr, nullptr, 6, 2);

    // bidirectional GRU recurrence -> outbuf
    gru_rec<<<dim3(128, 2), 512, 0, stream>>>(xg, WhhP, bhhP, outb);

    // word scores: atomicAdd tanh(out@WwT + bw) . pw
    gemm_k<1, bf16><<<2048 * 4, 256, 0, stream>>>(outb, kLD, k2H, 15,
                                                  WwT, 0, nullptr, 0, 0,
                                                  vecP, 0, vecP + 512, score, 4, 1);

    // softmax over T + weighted sum -> word_vec
    word_attn<<<kB, 256, 0, stream>>>(score, outb, wvf, wvb);

    // sentence scores (M=4096)
    gemm_k<1, bf16><<<32 * 4, 256, 0, stream>>>(wvb, kLD, k2H, 15,
                                                WsT, 0, nullptr, 0, 0,
                                                vecP + 1024, 0, vecP + 1536, s2, 4, 1);

    // sentence softmax + fc + scatter
    final_sent<<<kNB, 256, 0, stream>>>(s2, wvf, fcW, fcb, pairs, (float*)d_out);
}

// Round 4
// 2154.417 us; speedup vs baseline: 1.6397x; 1.0590x over previous
//
#include <hip/hip_runtime.h>
#include <math.h>

typedef __bf16 bf16;
typedef __bf16 bf16x8 __attribute__((ext_vector_type(8)));
typedef float f32x4 __attribute__((ext_vector_type(4)));
typedef float f4 __attribute__((ext_vector_type(4)));

constexpr int kNB = 512, kMS = 8, kT = 64, kH = 230, kIN = 360, kOUT = 53;
constexpr int kB  = kNB * kMS;            // 4096
constexpr long kBT = (long)kB * kT;       // 262144
constexpr int kNP  = 768;                 // packed 3H: 16 c-blocks * (r|z|n)*16
constexpr int kKIH = 384;                 // padded IN (12 * 32)
constexpr int kKHH = 256;                 // padded H  (8 * 32)
constexpr int k2H  = 460;
constexpr int kLD  = 464;                 // out/wv row stride (16B aligned)
constexpr int kKW  = 480;                 // padded 2H for K (15 * 32)
constexpr int kXS  = 772;                 // xs LDS row stride (gru)
constexpr int kHB  = 268;                 // hbf LDS row stride (gru)

// fast transcendentals (hardware v_exp_f32 / v_rcp_f32)
__device__ inline float fast_sigmoid(float x) {
    return __builtin_amdgcn_rcpf(1.f + __builtin_amdgcn_exp2f(x * -1.442695040888963f));
}
__device__ inline float fast_tanh(float x) {
    return 1.f - 2.f * __builtin_amdgcn_rcpf(1.f + __builtin_amdgcn_exp2f(x * 2.885390081777927f));
}

// async global->LDS DMA, 16B/lane; LDS dest = wave-uniform base + lane*16
__device__ inline void async16(const bf16* g, void* l) {
    __builtin_amdgcn_global_load_lds((const __attribute__((address_space(1))) void*)g,
                                     (__attribute__((address_space(3))) void*)l, 16, 0, 0);
}

// ---------------- workspace layout ----------------
constexpr long SZ_XG    = 2L * kB * kT * kNP * 2;
constexpr long SZ_OUT   = kBT * kLD * 2;               // bagb (201MB) aliases this (243MB)
constexpr long SZ_WIHP  = 2L * kNP * kKIH * 2;
constexpr long SZ_WHHP  = 2L * kNP * kKHH * 2;
constexpr long SZ_WWT   = 512L * kKW * 2;
constexpr long SZ_WST   = 512L * kKW * 2;
constexpr long SZ_BIHP  = 2L * kNP * 4;
constexpr long SZ_BHHP  = 2L * kNP * 4;
constexpr long SZ_VEC   = 2048L * 4;
constexpr long SZ_SCORE = kBT * 4;
constexpr long SZ_WVF   = (long)kB * kLD * 4;
constexpr long SZ_WVB   = (long)kB * kLD * 2;
constexpr long SZ_S2    = (long)kB * 4;

static inline long align256(long x) { return (x + 255) & ~255L; }

// ---------------- bag fp32 -> bf16, pad K 360->384 ----------------
__launch_bounds__(256)
__global__ void convert_bag(const float* __restrict__ bag, bf16* __restrict__ bagb)
{
    const long g = (long)blockIdx.x * 256 + threadIdx.x;   // one per 8-elem out group
    if (g >= kBT * 48) return;
    const long row = g / 48; const int cb = (int)(g % 48);
    bf16x8 v;
    if (cb < 45) {   // 360 = 45*8, all full groups
        const f4* p = (const f4*)(bag + row * kIN + cb * 8);
        f4 a = p[0], b = p[1];
        v[0]=(bf16)a[0]; v[1]=(bf16)a[1]; v[2]=(bf16)a[2]; v[3]=(bf16)a[3];
        v[4]=(bf16)b[0]; v[5]=(bf16)b[1]; v[6]=(bf16)b[2]; v[7]=(bf16)b[3];
    } else {
        v = bf16x8{};
    }
    *(bf16x8*)(bagb + row * kKIH + cb * 8) = v;
}

// ---------------- prep: pack/pad/transpose weights (fp32 -> bf16) ----------------
constexpr int R0 = 2 * kNP * kKIH;
constexpr int R1 = 2 * kNP * kKHH;
constexpr int R2 = 512 * kKW;
constexpr int R3 = 512 * kKW;
constexpr int R4 = 2 * kNP;
constexpr int R5 = 2 * kNP;
constexpr int R6 = 4 * 512;
constexpr long PREP_TOTAL = (long)R0 + R1 + R2 + R3 + R4 + R5 + R6;

__device__ inline bool unpack_n(int n, int& src) {
    int cb = n / 48, w = n % 48, g = w / 16, cc = w & 15;
    int c = cb * 16 + cc;
    src = g * kH + c;
    return c < kH;
}

__launch_bounds__(256)
__global__ void prep_pack(const float* __restrict__ Wihf, const float* __restrict__ Wihr,
                          const float* __restrict__ Whhf, const float* __restrict__ Whhr,
                          const float* __restrict__ bihf, const float* __restrict__ bihr,
                          const float* __restrict__ bhhf, const float* __restrict__ bhhr,
                          const float* __restrict__ Ww,  const float* __restrict__ bw,
                          const float* __restrict__ pw,
                          const float* __restrict__ Wsn, const float* __restrict__ bs,
                          const float* __restrict__ ps,
                          bf16* __restrict__ WihP, bf16* __restrict__ WhhP,
                          bf16* __restrict__ WwT,  bf16* __restrict__ WsT,
                          float* __restrict__ bihP, float* __restrict__ bhhP,
                          float* __restrict__ vecP)
{
    for (long id = (long)blockIdx.x * 256 + threadIdx.x; id < PREP_TOTAL;
         id += (long)gridDim.x * 256) {
        long i = id;
        if (i < R0) {
            int d = (int)(i / (kNP * kKIH)); int r = (int)(i % (kNP * kKIH));
            int n = r / kKIH, k = r % kKIH;
            int src; bool v = unpack_n(n, src) && (k < kIN);
            WihP[i] = v ? (bf16)(d ? Wihr : Wihf)[(long)src * kIN + k] : (bf16)0.f;
            continue;
        }
        i -= R0;
        if (i < R1) {
            int d = (int)(i / (kNP * kKHH)); int r = (int)(i % (kNP * kKHH));
            int n = r / kKHH, k = r % kKHH;
            int src; bool v = unpack_n(n, src) && (k < kH);
            WhhP[i] = v ? (bf16)(d ? Whhr : Whhf)[(long)src * kH + k] : (bf16)0.f;
            continue;
        }
        i -= R1;
        if (i < R2) {
            int n = (int)(i / kKW), k = (int)(i % kKW);
            WwT[i] = (n < k2H && k < k2H) ? (bf16)Ww[(long)k * k2H + n] : (bf16)0.f;
            continue;
        }
        i -= R2;
        if (i < R3) {
            int n = (int)(i / kKW), k = (int)(i % kKW);
            WsT[i] = (n < k2H && k < k2H) ? (bf16)Wsn[(long)k * k2H + n] : (bf16)0.f;
            continue;
        }
        i -= R3;
        if (i < R4) {
            int d = (int)(i / kNP), n = (int)(i % kNP);
            int src; bool v = unpack_n(n, src);
            bihP[i] = v ? (d ? bihr : bihf)[src] : 0.f;
            continue;
        }
        i -= R4;
        if (i < R5) {
            int d = (int)(i / kNP), n = (int)(i % kNP);
            int src; bool v = unpack_n(n, src);
            bhhP[i] = v ? (d ? bhhr : bhhf)[src] : 0.f;
            continue;
        }
        i -= R5;
        {
            int which = (int)(i / 512), n = (int)(i % 512);
            const float* s = (which == 0) ? bw : (which == 1) ? pw : (which == 2) ? bs : ps;
            vecP[i] = (n < k2H) ? s[n] : 0.f;
        }
    }
}

// ---------------- 128x128 bf16 MFMA GEMM, DMA-staged (m97 structure) ----------------
// A: (M, lda) bf16, readable for ksteps*32 cols per row (padded or overrun-safe).
// Bp: (nblks*128, ksteps*32) bf16 row-major pre-padded. MODE 0: C=bf16(acc+bias).
// MODE 2: time-major remap row=b*64+t -> t*4096+b. MODE 1: score[row] += tanh(acc+bias).proj
template<int MODE>
__launch_bounds__(256)
__global__ void gemm_k(const bf16* __restrict__ A, int lda, int ksteps,
                       const bf16* __restrict__ Bp, long bStride,
                       bf16* __restrict__ C, int ldc, long cStride,
                       const float* __restrict__ bias, int biasStride,
                       const float* __restrict__ proj,
                       float* __restrict__ score,
                       int nblks, int zc)
{
    __shared__ bf16 As[128][32];
    __shared__ bf16 Bs[128][32];
    const int tid = threadIdx.x;
    // block decode: mi in low bits => consecutive blocks share one A panel (L2 reuse)
    const int grp = 8 * nblks * zc;
    const int mg = blockIdx.x / grp, sub = blockIdx.x % grp;
    const int mi = sub & 7, rest = sub >> 3;
    const int nblk = rest % nblks, z = rest / nblks;
    const int mblk = mg * 8 + mi;

    const bf16* Bz = Bp + (long)z * bStride;
    const int rowA0 = mblk * 128, rowB0 = nblk * 128;
    const int lane = tid & 63, wave = tid >> 6;
    const int wm = wave >> 1, wn = wave & 1;
    const int quad = lane >> 4, l16 = lane & 15;
    const int ldb = ksteps * 32;

    // DMA source geometry: lane -> (row = lane>>2 within 16-row panel, colblk = lane&3)
    const int sr = lane >> 2, scb = (lane & 3) * 8;
    const bf16* gA0 = A + (long)(rowA0 + wave * 16 + sr) * lda + scb;
    const bf16* gA1 = gA0 + (long)64 * lda;
    const bf16* gB0 = Bz + (long)(rowB0 + wave * 16 + sr) * ldb + scb;
    const bf16* gB1 = gB0 + (long)64 * ldb;
    void* lA0 = &As[wave * 16][0];
    void* lA1 = &As[64 + wave * 16][0];
    void* lB0 = &Bs[wave * 16][0];
    void* lB1 = &Bs[64 + wave * 16][0];

    f32x4 acc[4][4] = {};

    for (int ks = 0; ks < ksteps; ++ks) {
        const int kk = ks * 32;
        async16(gA0 + kk, lA0);
        async16(gA1 + kk, lA1);
        async16(gB0 + kk, lB0);
        async16(gB1 + kk, lB1);
        __syncthreads();   // drains vmcnt (DMA) for all waves
        bf16x8 af[4], bfr[4];
#pragma unroll
        for (int mt = 0; mt < 4; ++mt) af[mt] = *(const bf16x8*)&As[wm * 64 + mt * 16 + l16][quad * 8];
#pragma unroll
        for (int nt = 0; nt < 4; ++nt) bfr[nt] = *(const bf16x8*)&Bs[wn * 64 + nt * 16 + l16][quad * 8];
#pragma unroll
        for (int mt = 0; mt < 4; ++mt)
#pragma unroll
            for (int nt = 0; nt < 4; ++nt)
                acc[mt][nt] = __builtin_amdgcn_mfma_f32_16x16x32_bf16(af[mt], bfr[nt], acc[mt][nt], 0, 0, 0);
        __syncthreads();   // frag reads done before next step's DMA lands
    }

    if constexpr (MODE == 0 || MODE == 2) {
        bf16* Cz = C + (long)z * cStride;
        const float* bz = bias + (long)z * biasStride;
#pragma unroll
        for (int mt = 0; mt < 4; ++mt)
#pragma unroll
            for (int nt = 0; nt < 4; ++nt) {
                const int col = rowB0 + wn * 64 + nt * 16 + l16;
                const float bv = bz[col];
#pragma unroll
                for (int r = 0; r < 4; ++r) {
                    const int row = rowA0 + wm * 64 + mt * 16 + quad * 4 + r;
                    const int rowp = (MODE == 2) ? ((row & 63) * kB + (row >> 6)) : row;
                    Cz[(long)rowp * ldc + col] = (bf16)(acc[mt][nt][r] + bv);
                }
            }
    } else {
#pragma unroll
        for (int mt = 0; mt < 4; ++mt)
#pragma unroll
            for (int r = 0; r < 4; ++r) {
                float s = 0.f;
#pragma unroll
                for (int nt = 0; nt < 4; ++nt) {
                    const int col = rowB0 + wn * 64 + nt * 16 + l16;
                    s += fast_tanh(acc[mt][nt][r] + bias[col]) * proj[col];
                }
                for (int m = 1; m < 16; m <<= 1) s += __shfl_xor(s, m, 64);
                if (l16 == 0) {
                    const int row = rowA0 + wm * 64 + mt * 16 + quad * 4 + r;
                    atomicAdd(&score[row], s);
                }
            }
    }
}

// ---------------- GRU recurrence: 512 thr, xg prefetch, h in regs ----------------
__launch_bounds__(512)
__global__ void gru_rec(const bf16* __restrict__ xg,   // [2][64][4096][768] TIME-MAJOR
                        const bf16* __restrict__ Whh,  // [2][768][256] packed/padded
                        const float* __restrict__ bhh, // [2][768] packed
                        bf16* __restrict__ outbuf)     // [262144][464], col = d*230 + c
{
    __shared__ bf16 hbf[32][kHB];
    __shared__ bf16 xs[32][kXS];
    const int tid = threadIdx.x;
    const int d = blockIdx.y;
    const int row0 = blockIdx.x * 32;
    const int lane = tid & 63, wave = tid >> 6;   // 8 waves
    const int quad = lane >> 4, l16 = lane & 15;
    const int cb0 = wave * 2;

    for (int i = tid; i < 32 * kHB; i += 512) (&hbf[0][0])[i] = (bf16)0.f;

    const bf16* xgd = xg + (long)d * ((long)kT * kB * kNP);
    const bf16* Wd  = Whh + (long)d * ((long)kNP * kKHH);
    const float* bd = bhh + (long)d * kNP;

    float hreg[2][2][4] = {};
    float bdr[2], bdz[2], bdn[2];
#pragma unroll
    for (int cbl = 0; cbl < 2; ++cbl) {
        const int cb = cb0 + cbl;
        bdr[cbl] = bd[cb * 48 + l16];
        bdz[cbl] = bd[cb * 48 + 16 + l16];
        bdn[cbl] = bd[cb * 48 + 32 + l16];
    }

    const int xr_row = tid >> 4, xr_col = (tid & 15) * 48;

    bf16x8 pf[6];
    {
        const int t0 = d ? kT - 1 : 0;
        const bf16* src = xgd + ((long)t0 * kB + row0) * kNP + (long)tid * 48;
#pragma unroll
        for (int j = 0; j < 6; ++j) pf[j] = *(const bf16x8*)(src + j * 8);
    }
    __syncthreads();

    for (int it = 0; it < kT; ++it) {
        const int t = d ? (kT - 1 - it) : it;
#pragma unroll
        for (int j = 0; j < 6; ++j) *(bf16x8*)&xs[xr_row][xr_col + j * 8] = pf[j];

        f32x4 acc[2][2][3] = {};
#pragma unroll
        for (int ks = 0; ks < 8; ++ks) {
            bf16x8 af0 = *(const bf16x8*)&hbf[l16][ks * 32 + quad * 8];
            bf16x8 af1 = *(const bf16x8*)&hbf[16 + l16][ks * 32 + quad * 8];
#pragma unroll
            for (int cbl = 0; cbl < 2; ++cbl)
#pragma unroll
                for (int g = 0; g < 3; ++g) {
                    const int n = (cb0 + cbl) * 48 + g * 16 + l16;
                    bf16x8 bfr = *(const bf16x8*)(Wd + (long)n * kKHH + ks * 32 + quad * 8);
                    acc[0][cbl][g] = __builtin_amdgcn_mfma_f32_16x16x32_bf16(af0, bfr, acc[0][cbl][g], 0, 0, 0);
                    acc[1][cbl][g] = __builtin_amdgcn_mfma_f32_16x16x32_bf16(af1, bfr, acc[1][cbl][g], 0, 0, 0);
                }
        }
        if (it + 1 < kT) {
            const int tn = d ? (kT - 2 - it) : (it + 1);
            const bf16* src = xgd + ((long)tn * kB + row0) * kNP + (long)tid * 48;
#pragma unroll
            for (int j = 0; j < 6; ++j) pf[j] = *(const bf16x8*)(src + j * 8);
        }
        __syncthreads();

#pragma unroll
        for (int cbl = 0; cbl < 2; ++cbl) {
            const int cb = cb0 + cbl;
            const int c = cb * 16 + l16;
            if (c < kH) {
#pragma unroll
                for (int mt = 0; mt < 2; ++mt)
#pragma unroll
                    for (int r = 0; r < 4; ++r) {
                        const int rl = mt * 16 + quad * 4 + r;
                        const float xr = (float)xs[rl][cb * 48 + l16];
                        const float xz = (float)xs[rl][cb * 48 + 16 + l16];
                        const float xn = (float)xs[rl][cb * 48 + 32 + l16];
                        const float rgate = fast_sigmoid(xr + acc[mt][cbl][0][r] + bdr[cbl]);
                        const float zgate = fast_sigmoid(xz + acc[mt][cbl][1][r] + bdz[cbl]);
                        const float ngate = fast_tanh(xn + rgate * (acc[mt][cbl][2][r] + bdn[cbl]));
                        const float h2 = (1.f - zgate) * ngate + zgate * hreg[mt][cbl][r];
                        hreg[mt][cbl][r] = h2;
                        hbf[rl][c] = (bf16)h2;
                        outbuf[((long)(row0 + rl) * kT + t) * kLD + d * kH + c] = (bf16)h2;
                    }
            }
        }
        __syncthreads();
    }
}

// ---------------- word attention: softmax over T + weighted sum (coalesced) ----------------
__launch_bounds__(256)
__global__ void word_attn(const float* __restrict__ score, const bf16* __restrict__ outbuf,
                          float* __restrict__ wvf, bf16* __restrict__ wvb)
{
    const int b = blockIdx.x, tid = threadIdx.x;
    __shared__ float alpha[kT];
    if (tid < 64) {
        float v = score[b * kT + tid];
        float m = v;
        for (int off = 32; off; off >>= 1) m = fmaxf(m, __shfl_xor(m, off, 64));
        float e = __builtin_amdgcn_exp2f((v - m) * 1.442695040888963f);
        float s = e;
        for (int off = 32; off; off >>= 1) s += __shfl_xor(s, off, 64);
        alpha[tid] = e / s;
    }
    __syncthreads();
    const bf16* base = outbuf + (long)b * kT * kLD;
    float a0 = 0.f, a1 = 0.f;
    const int c0 = tid, c1 = tid + 256;
#pragma unroll 4
    for (int t = 0; t < kT; ++t) {
        const float al = alpha[t];
        a0 += al * (float)base[t * kLD + c0];
        if (c1 < k2H) a1 += al * (float)base[t * kLD + c1];
    }
    wvf[(long)b * kLD + c0] = a0;
    wvb[(long)b * kLD + c0] = (bf16)a0;
    if (c1 < k2H) {
        wvf[(long)b * kLD + c1] = a1;
        wvb[(long)b * kLD + c1] = (bf16)a1;
    }
}

// ---------------- sentence softmax + weighted sum + fc + scatter (fp32 out) ----------------
__launch_bounds__(256)
__global__ void final_sent(const float* __restrict__ score2, const float* __restrict__ wvf,
                           const float* __restrict__ fcW, const float* __restrict__ fcb,
                           const int* __restrict__ pairs, float* __restrict__ outp)
{
    const int nb = blockIdx.x, tid = threadIdx.x;
    __shared__ float beta[kMS];
    __shared__ float sv[k2H];
    if (tid == 0) {
        float m = -1e30f;
        for (int s = 0; s < kMS; ++s) m = fmaxf(m, score2[nb * kMS + s]);
        float e[kMS], sum = 0.f;
        for (int s = 0; s < kMS; ++s) { e[s] = expf(score2[nb * kMS + s] - m); sum += e[s]; }
        for (int s = 0; s < kMS; ++s) beta[s] = e[s] / sum;
    }
    __syncthreads();
    for (int c = tid; c < k2H; c += 256) {
        float a = 0.f;
#pragma unroll
        for (int s = 0; s < kMS; ++s) a += beta[s] * wvf[(long)(nb * kMS + s) * kLD + c];
        sv[c] = a;
    }
    __syncthreads();
    const int lane = tid & 63, wave = tid >> 6;
    const long base = ((long)pairs[nb * 3] * 64 + pairs[nb * 3 + 1] * 8 + pairs[nb * 3 + 2]) * kOUT;
    for (int o = wave; o < kOUT; o += 4) {
        float p = 0.f;
        for (int c = lane; c < k2H; c += 64) p += sv[c] * fcW[(long)o * k2H + c];
        for (int off = 32; off; off >>= 1) p += __shfl_xor(p, off, 64);
        if (lane == 0) outp[base + o] = p + fcb[o];
    }
}

// ---------------- launch ----------------
extern "C" void kernel_launch(void* const* d_in, const int* in_sizes, int n_in,
                              void* d_out, int out_size, void* d_ws, size_t ws_size,
                              hipStream_t stream)
{
    const float* bag  = (const float*)d_in[0];
    const float* Wihf = (const float*)d_in[1];
    const float* Whhf = (const float*)d_in[2];
    const float* bihf = (const float*)d_in[3];
    const float* bhhf = (const float*)d_in[4];
    const float* Wihr = (const float*)d_in[5];
    const float* Whhr = (const float*)d_in[6];
    const float* bihr = (const float*)d_in[7];
    const float* bhhr = (const float*)d_in[8];
    const float* Ww   = (const float*)d_in[9];
    const float* bw   = (const float*)d_in[10];
    const float* pw   = (const float*)d_in[11];
    const float* Wsn  = (const float*)d_in[12];
    const float* bs   = (const float*)d_in[13];
    const float* ps   = (const float*)d_in[14];
    const float* fcW  = (const float*)d_in[15];
    const float* fcb  = (const float*)d_in[16];
    const int* pairs  = (const int*)d_in[17];

    char* ws = (char*)d_ws;
    long off = 0;
    auto alloc = [&](long sz) { void* p = ws + off; off += align256(sz); return p; };
    bf16* xg    = (bf16*)alloc(SZ_XG);
    bf16* outb  = (bf16*)alloc(SZ_OUT);
    bf16* bagb  = outb;   // alias: bagb live only before gru_rec writes outb
    bf16* WihP  = (bf16*)alloc(SZ_WIHP);
    bf16* WhhP  = (bf16*)alloc(SZ_WHHP);
    bf16* WwT   = (bf16*)alloc(SZ_WWT);
    bf16* WsT   = (bf16*)alloc(SZ_WST);
    float* bihP = (float*)alloc(SZ_BIHP);
    float* bhhP = (float*)alloc(SZ_BHHP);
    float* vecP = (float*)alloc(SZ_VEC);
    float* score= (float*)alloc(SZ_SCORE);
    float* wvf  = (float*)alloc(SZ_WVF);
    bf16* wvb   = (bf16*)alloc(SZ_WVB);
    float* s2   = (float*)alloc(SZ_S2);
    if ((size_t)off > ws_size) return;

    hipMemsetAsync(d_out, 0, (size_t)out_size * 4, stream);
    hipMemsetAsync(score, 0, SZ_SCORE, stream);
    hipMemsetAsync(s2, 0, SZ_S2, stream);

    convert_bag<<<(int)((kBT * 48 + 255) / 256), 256, 0, stream>>>(bag, bagb);

    prep_pack<<<5781, 256, 0, stream>>>(Wihf, Wihr, Whhf, Whhr, bihf, bihr, bhhf, bhhr,
                                        Ww, bw, pw, Wsn, bs, ps,
                                        WihP, WhhP, WwT, WsT, bihP, bhhP, vecP);

    // input projection -> xg TIME-MAJOR: xg[d][t][b][:] = bagb row (b*64+t) @ WihP[d]^T + bihP[d]
    gemm_k<2><<<2048 * 6 * 2, 256, 0, stream>>>(bagb, kKIH, 12,
                                                WihP, (long)kNP * kKIH,
                                                xg, kNP, (long)kT * kB * kNP,
                                                bihP, kNP, nullptr, nullptr, 6, 2);

    // bidirectional GRU recurrence -> outbuf (overwrites bagb alias)
    gru_rec<<<dim3(128, 2), 512, 0, stream>>>(xg, WhhP, bhhP, outb);

    // word scores: score[row] += tanh(out@WwT + bw) . pw
    gemm_k<1><<<2048 * 4, 256, 0, stream>>>(outb, kLD, 15,
                                            WwT, 0, nullptr, 0, 0,
                                            vecP, 0, vecP + 512, score, 4, 1);

    // softmax over T + weighted sum -> word_vec
    word_attn<<<kB, 256, 0, stream>>>(score, outb, wvf, wvb);

    // sentence scores (M=4096)
    gemm_k<1><<<32 * 4, 256, 0, stream>>>(wvb, kLD, 15,
                                          WsT, 0, nullptr, 0, 0,
                                          vecP + 1024, 0, vecP + 1536, s2, 4, 1);

    // sentence softmax + fc + scatter
    final_sent<<<kNB, 256, 0, stream>>>(s2, wvf, fcW, fcb, pairs, (float*)d_out);
}